// Round 5
// baseline (1109.324 us; speedup 1.0000x reference)
//
#include <hip/hip_runtime.h>
#include <hip/hip_bf16.h>

#define NN 3136
#define CC 512
#define BBATCH 8

typedef __attribute__((ext_vector_type(8))) short short8;
typedef __attribute__((ext_vector_type(4))) float f32x4;
typedef __attribute__((ext_vector_type(4))) unsigned short ush4;

static __device__ __forceinline__ unsigned short f2bf(float f) {
    union { float f; unsigned int u; } v; v.f = f;
    unsigned int u = v.u;
    return (unsigned short)((u + 0x7fffu + ((u >> 16) & 1u)) >> 16); // RNE
}

// ---------------- norms: inv[t][b][n] = 1/max(||f_t[b,:,n]||, 1e-12) ----------------
__global__ void norms_k(const float* __restrict__ f1, const float* __restrict__ f2,
                        const float* __restrict__ f3, float* __restrict__ inv) {
    int g = blockIdx.x * 256 + threadIdx.x;          // < 3*8*3136 = 75264
    int t = g / (BBATCH * NN);
    int r = g - t * (BBATCH * NN);
    int b = r / NN;
    int n = r - b * NN;
    const float* f = (t == 0) ? f1 : (t == 1) ? f2 : f3;
    const float* p = f + (size_t)b * CC * NN + n;
    float ss = 0.f;
#pragma unroll 8
    for (int c = 0; c < CC; ++c) { float x = p[(size_t)c * NN]; ss = fmaf(x, x, ss); }
    inv[g] = 1.0f / fmaxf(sqrtf(ss), 1e-12f);
}

// ---------------- init: out = fm1 ----------------
__global__ void init_k(const float4* __restrict__ src, float4* __restrict__ dst) {
    int g = blockIdx.x * 256 + threadIdx.x;
    dst[g] = src[g];
}

// ---------------- fused attention branch, out += 0.001 * (fk @ softmax(-q^k^)^T) ----------------
// Per WG: one (batch, branch, 64-row Q-tile). K^T/V double-buffered in LDS,
// Q B-frags in registers, P routed through LDS, scores bounded in [-1,1] so
// softmax needs no running max (p = exp(s) directly, denominator accumulated).
static constexpr int KTOFF = 16384;   // ushort offset of KT buf1
static constexpr int VBASE = 32768;   // ushort offset of V bufs
static constexpr int VOFF  = 20480;   // ushort offset of V buf1 within VBASE
static constexpr int PBASE = VBASE + 2 * VOFF;

__launch_bounds__(512, 2)
__global__ void attn_fused_k(const float* __restrict__ fq_all,
                             const float* __restrict__ f2_all,
                             const float* __restrict__ f3_all,
                             const float* __restrict__ invws,
                             float* __restrict__ out) {
    // LDS: kt double-buffer 2x32KB, v double-buffer 2x40KB, p 5KB  (~149KB)
    __shared__ __align__(16) unsigned short smem[2 * 16384 + 2 * 20480 + 64 * 40];
    __shared__ float denbuf[8][16];

    unsigned short* pp = smem + PBASE;               // [64][40]
    unsigned short* qstage = smem;                   // 32768 ushorts (aliases kt bufs)

    const int tid = threadIdx.x;
    const int w = tid >> 6, l = tid & 63;
    const int u = blockIdx.x;
    const int batch = u & 7;                          // 8 batches -> 8 XCDs (round-robin heuristic)
    const int unit = u >> 3;                          // 0..97
    const int br = unit & 1;
    const int qt = unit >> 1;                         // 0..48
    const int n0 = qt * 64;

    const float* fq = fq_all + (size_t)batch * CC * NN;
    const float* fk = (br ? f3_all : f2_all) + (size_t)batch * CC * NN;
    const float* inv1 = invws + batch * NN;
    const float* invk = invws + (1 + br) * (BBATCH * NN) + batch * NN;

    // ---- Q stage: [n][c] bf16, value = -f1*inv1 (sign folded), XOR-swizzled rows
    {
        int n = tid & 63, grp = tid >> 6;             // grp 0..7
        float s = -inv1[n0 + n];
        const float* src = fq + n0 + n;
        int sw = (n & 7) << 3;
#pragma unroll 4
        for (int ssi = 0; ssi < 16; ++ssi) {
            int cb = grp * 4 + 32 * ssi;
            float x0 = src[(size_t)(cb + 0) * NN], x1 = src[(size_t)(cb + 1) * NN];
            float x2 = src[(size_t)(cb + 2) * NN], x3 = src[(size_t)(cb + 3) * NN];
            ush4 y = { f2bf(x0 * s), f2bf(x1 * s), f2bf(x2 * s), f2bf(x3 * s) };
            *(ush4*)&qstage[n * 512 + (cb ^ sw)] = y;
        }
    }
    __syncthreads();

    // ---- Q fragments to registers: wave w owns n-cols 16*(w&3)..+15, all 16 k-steps
    short8 qf[16];
    {
        int nQ = 16 * (w & 3) + (l & 15);
        int sw = (nQ & 7) << 3;
#pragma unroll
        for (int ks = 0; ks < 16; ++ks)
            qf[ks] = *(const short8*)&qstage[nQ * 512 + ((ks * 32 + ((l >> 4) << 3)) ^ sw)];
    }
    __syncthreads();

    // ---- staging: K^T [m][c] (inv2-scaled, swizzled) + V [c][m] (raw, stride 40)
    auto stage = [&](int it, int bb2) {
        int m = tid & 31, grp = tid >> 5;             // grp 0..15
        int m0 = it * 32;
        float sk = invk[m0 + m];
        const float* src = fk + m0 + m;
        unsigned short* KT = smem + (bb2 ? KTOFF : 0);
        unsigned short* V  = smem + VBASE + (bb2 ? VOFF : 0);
        int swm = (m & 7) << 3;
        float xbuf[32];
#pragma unroll
        for (int ssi = 0; ssi < 8; ++ssi) {
            int cb = grp * 4 + 64 * ssi;
            xbuf[ssi * 4 + 0] = src[(size_t)(cb + 0) * NN];
            xbuf[ssi * 4 + 1] = src[(size_t)(cb + 1) * NN];
            xbuf[ssi * 4 + 2] = src[(size_t)(cb + 2) * NN];
            xbuf[ssi * 4 + 3] = src[(size_t)(cb + 3) * NN];
        }
#pragma unroll
        for (int ssi = 0; ssi < 8; ++ssi) {
            int cb = grp * 4 + 64 * ssi;
            float x0 = xbuf[ssi * 4 + 0], x1 = xbuf[ssi * 4 + 1];
            float x2 = xbuf[ssi * 4 + 2], x3 = xbuf[ssi * 4 + 3];
            ush4 y = { f2bf(x0 * sk), f2bf(x1 * sk), f2bf(x2 * sk), f2bf(x3 * sk) };
            *(ush4*)&KT[m * 512 + (cb ^ swm)] = y;
            V[(cb + 0) * 40 + m] = f2bf(x0);
            V[(cb + 1) * 40 + m] = f2bf(x1);
            V[(cb + 2) * 40 + m] = f2bf(x2);
            V[(cb + 3) * 40 + m] = f2bf(x3);
        }
    };

    f32x4 acc[16];
#pragma unroll
    for (int k = 0; k < 16; ++k) acc[k] = (f32x4){0.f, 0.f, 0.f, 0.f};
    float den_part = 0.f;

    stage(0, 0);

    const int mt = w >> 2, nt = w & 3;
    const int g = l >> 4, li = l & 15;
    const int mA = 16 * mt + li;                      // score A-row (m)
    const int swA = (mA & 7) << 3;
    const int nP = 16 * nt + li;                      // n index for P / den / output col

    for (int it = 0; it < 98; ++it) {
        int bb2 = it & 1;
        __syncthreads();                              // buf[bb2] staged; P free (prev PV done)

        // scores: D[m][n] = sum_c K^T[m,c] * Qneg[c,n]  (s = -q^.k^ already)
        f32x4 sacc = (f32x4){0.f, 0.f, 0.f, 0.f};
        const unsigned short* KT = smem + (bb2 ? KTOFF : 0);
#pragma unroll
        for (int ks = 0; ks < 16; ++ks) {
            short8 af = *(const short8*)&KT[mA * 512 + ((ks * 32 + (g << 3)) ^ swA)];
            sacc = __builtin_amdgcn_mfma_f32_16x16x32_bf16(af, qf[ks], sacc, 0, 0, 0);
        }
        // p = exp(s); s in [-1,1] so no max-subtraction needed
        float p0 = __expf(sacc[0]), p1 = __expf(sacc[1]);
        float p2 = __expf(sacc[2]), p3 = __expf(sacc[3]);
        den_part += (p0 + p1) + (p2 + p3);
        ush4 pw = { f2bf(p0), f2bf(p1), f2bf(p2), f2bf(p3) };
        *(ush4*)&pp[nP * 40 + 16 * mt + 4 * g] = pw;  // P[n][m], m rows 16*mt+4g..+3

        if (it != 97) stage(it + 1, bb2 ^ 1);
        __syncthreads();                              // P visible; stage writes done

        // PV: O^T[c][n] += sum_m V[c,m] * P^T[m,n]
        const unsigned short* V = smem + VBASE + (bb2 ? VOFF : 0);
        short8 bfr = *(const short8*)&pp[nP * 40 + (g << 3)];
#pragma unroll
        for (int k = 0; k < 16; ++k) {
            int cR = 16 * (16 * mt + k) + li;         // A row (c), wave owns 16 c-tiles
            short8 af = *(const short8*)&V[cR * 40 + (g << 3)];
            acc[k] = __builtin_amdgcn_mfma_f32_16x16x32_bf16(af, bfr, acc[k], 0, 0, 0);
        }
    }

    // ---- den reduction: sum over 4 lane-groups, then over the 2 mt-waves
    den_part += __shfl_xor(den_part, 16);
    den_part += __shfl_xor(den_part, 32);
    if (l < 16) denbuf[w][l] = den_part;
    __syncthreads();
    float dtot = denbuf[nt][li] + denbuf[4 + nt][li];
    float scale = 0.001f / dtot;

    float* op = out + (size_t)batch * CC * NN + n0 + nP;
#pragma unroll
    for (int k = 0; k < 16; ++k) {
        int cbase = 16 * (16 * mt + k) + 4 * g;
#pragma unroll
        for (int r = 0; r < 4; ++r)
            atomicAdd(&op[(size_t)(cbase + r) * NN], acc[k][r] * scale);
    }
}

extern "C" void kernel_launch(void* const* d_in, const int* in_sizes, int n_in,
                              void* d_out, int out_size, void* d_ws, size_t ws_size,
                              hipStream_t stream) {
    (void)in_sizes; (void)n_in; (void)out_size; (void)ws_size;
    const float* f1 = (const float*)d_in[0];
    const float* f2 = (const float*)d_in[1];
    const float* f3 = (const float*)d_in[2];
    float* out = (float*)d_out;
    float* inv = (float*)d_ws;                        // 3*8*3136 floats = 301 KB

    norms_k<<<294, 256, 0, stream>>>(f1, f2, f3, inv);          // 75264 threads exactly
    init_k<<<12544, 256, 0, stream>>>((const float4*)f1, (float4*)out);
    attn_fused_k<<<784, 512, 0, stream>>>(f1, f2, f3, inv, out); // 8 batch x 49 qtile x 2 branch
}